// Round 9
// baseline (200.896 us; speedup 1.0000x reference)
//
#include <hip/hip_runtime.h>

typedef _Float16 half_t;
typedef _Float16 half8  __attribute__((ext_vector_type(8)));
typedef _Float16 half4v __attribute__((ext_vector_type(4)));
typedef float    f32x16 __attribute__((ext_vector_type(16)));
typedef float    f32x4  __attribute__((ext_vector_type(4)));

#define DEVI static __device__ __forceinline__

constexpr int B_  = 16384;
constexpr int T_  = 28;
constexpr int IN_ = 28;
constexpr int H_  = 128;
constexpr int C_  = 11;
constexpr int BT  = 64;    // batch rows per block; grid = 256 = 1 block/CU
constexpr int NT  = 768;   // 12 waves: 4x L0 (slim), 4x L1 (2m-reuse), 4x L2 (2m-reuse)
constexpr int HSTR = 136;  // LDS stride (halves): 272B rows, 16B-aligned
constexpr int XSTR = 40;

constexpr int HBUF = BT * HSTR;
constexpr int XBUF = BT * XSTR;
constexpr int SM_HALVES = 6 * HBUF + 2 * XBUF;  // h[3][2] + xin[2]
constexpr size_t SM_BYTES = (size_t)SM_HALVES * 2 + 3 * H_ * 4;  // + bias = 116224 B

DEVI f32x16 mfma(half8 a, half8 b, f32x16 c) {
  return __builtin_amdgcn_mfma_f32_32x32x16_f16(a, b, c, 0, 0, 0);
}

DEVI half8 frag(const half_t* base, int kc) { return *(const half8*)(base + kc * 16); }

// A-fragments, one 32-row m-tile of a 128x128 row-major fp32 matrix.
// A layout (32x32x16 f16, validated R2-R8): lane holds A[m=lane&31][k=(lane>>5)*8+j].
DEVI void loadw8(half8 d[8], const float* __restrict__ w, int mrow, int hf) {
  const float* p = w + mrow * H_ + hf * 8;
#pragma unroll
  for (int kc = 0; kc < 8; ++kc) {
    half8 f;
#pragma unroll
    for (int j = 0; j < 8; ++j) f[j] = (half_t)p[kc * 16 + j];
    d[kc] = f;
  }
}

// h = relu(acc + bias) -> hout[b=ncol0+l31][n=mrow0+...].
// C/D layout (HW-verified m74/m101): col=lane&31, row=(reg&3)+8*(reg>>2)+4*(lane>>5).
DEVI void epi1(half_t* __restrict__ hout, const float* __restrict__ bl,
               f32x16 a, int mrow0, int ncol0, int l31, int hf) {
#pragma unroll
  for (int rq = 0; rq < 4; ++rq) {
    const int n0 = mrow0 + rq * 8 + hf * 4;
    const f32x4 b4 = *(const f32x4*)&bl[n0];
    half4v h4;
#pragma unroll
    for (int ri = 0; ri < 4; ++ri)
      h4[ri] = (half_t)fmaxf(a[rq * 4 + ri] + b4[ri], 0.0f);
    *(half4v*)&hout[(ncol0 + l31) * HSTR + n0] = h4;
  }
}

// Shared body for L1/L2 reuse waves: 2 m-tiles x 1 n-tile; each B-frag read
// feeds 2 MFMAs (read:MFMA = 1:2 -> LDS pipe 2016 cyc < MFMA 2688 per CU-iter).
DEVI void mm2m(const half_t* __restrict__ bi, const half_t* __restrict__ br,
               const half8 wi[2][8], const half8 wh[2][8],
               f32x16& a0r, f32x16& a1r) {
  f32x16 a0 = {}, a1 = {};
#pragma unroll
  for (int kc = 0; kc < 8; ++kc) {
    const half8 b = frag(bi, kc);
    a0 = mfma(wi[0][kc], b, a0);
    a1 = mfma(wi[1][kc], b, a1);
  }
#pragma unroll
  for (int kc = 0; kc < 8; ++kc) {
    const half8 b = frag(br, kc);
    a0 = mfma(wh[0][kc], b, a0);
    a1 = mfma(wh[1][kc], b, a1);
  }
  a0r = a0;
  a1r = a1;
}

__global__ __launch_bounds__(NT) __attribute__((amdgpu_waves_per_eu(3)))
void rnn_pipe(const float* __restrict__ x,
              const float* __restrict__ wih0, const float* __restrict__ whh0,
              const float* __restrict__ bih0, const float* __restrict__ bhh0,
              const float* __restrict__ wih1, const float* __restrict__ whh1,
              const float* __restrict__ bih1, const float* __restrict__ bhh1,
              const float* __restrict__ wih2, const float* __restrict__ whh2,
              const float* __restrict__ bih2, const float* __restrict__ bhh2,
              const float* __restrict__ fcw, const float* __restrict__ fcb,
              float* __restrict__ out)
{
  extern __shared__ __align__(16) char smraw[];
  half_t* hs   = (half_t*)smraw;
  float*  bias = (float*)(hs + SM_HALVES);
#define HB(l, b) (hs + ((l) * 2 + (b)) * HBUF)
#define XB(b)    (hs + 6 * HBUF + (b) * XBUF)

  const int tid  = threadIdx.x;
  const int b0   = blockIdx.x * BT;
  const int lane = tid & 63;
  const int wid  = tid >> 6;
  const int l31  = lane & 31;
  const int hf   = lane >> 5;

  // ---- init: zero all LDS buffers (h_{-1}=0, x pad cols=0), stage biases ----
  for (int i = tid; i < SM_HALVES / 2; i += NT) ((unsigned int*)hs)[i] = 0u;
  if (tid < H_) {
    bias[tid]          = bih0[tid] + bhh0[tid];
    bias[H_ + tid]     = bih1[tid] + bhh1[tid];
    bias[2 * H_ + tid] = bih2[tid] + bhh2[tid];
  }
  __syncthreads();
  if (tid < 512) {  // stage x[t=0] into XB(0)
    const int row = tid >> 3, ch = tid & 7;
    if (ch < 7) {
      const f32x4 v = *(const f32x4*)(x + (size_t)(b0 + row) * (T_ * IN_) + ch * 4);
      half4v h4;
#pragma unroll
      for (int j = 0; j < 4; ++j) h4[j] = (half_t)v[j];
      *(half4v*)&XB(0)[row * XSTR + ch * 4] = h4;
    }
  }
  __syncthreads();

  // ===== wave-specialized pipeline: iter i computes h0[i], h1[i-1], h2[i-2] =====
  // Reads hit parity p, writes parity np: ONE barrier/iter; 30 barriers per branch.
  if (wid < 4) {
    // ---- L0 (slim): 1 m-tile, 2 n-tiles; also stages x[t=i+1] (tids 0..255) ----
    const int mt = wid;
    half8 ai0[2], ah0[8];
    loadw8(ah0, whh0, mt * 32 + l31, hf);
#pragma unroll
    for (int kc = 0; kc < 2; ++kc) {  // wih0: K=28 padded to 32 with zeros
      half8 f;
#pragma unroll
      for (int j = 0; j < 8; ++j) {
        const int k = kc * 16 + hf * 8 + j;
        f[j] = (k < IN_) ? (half_t)wih0[(mt * 32 + l31) * IN_ + k] : (half_t)0.0f;
      }
      ai0[kc] = f;
    }
    const int xrow = tid >> 3, xch = tid & 7;  // tid<256: rows 0..31 (+32 second chunk)
    for (int i = 0; i < T_ + 2; ++i) {
      const int p = i & 1, np = p ^ 1;
      const bool xact = (xch < 7) && (i + 1 < T_);
      f32x4 xq0, xq1;
      if (xact) {  // issue global loads early; consumed at iteration end
        const float* xp = x + (size_t)(i + 1) * IN_ + xch * 4;
        xq0 = *(const f32x4*)(xp + (size_t)(b0 + xrow) * (T_ * IN_));
        xq1 = *(const f32x4*)(xp + (size_t)(b0 + xrow + 32) * (T_ * IN_));
      }
      if (i < T_) {
        const half_t* bx0 = XB(p) + l31 * XSTR + hf * 8;
        const half_t* bx1 = XB(p) + (32 + l31) * XSTR + hf * 8;
        const half_t* bh0 = HB(0, p) + l31 * HSTR + hf * 8;
        const half_t* bh1 = HB(0, p) + (32 + l31) * HSTR + hf * 8;
        f32x16 a0 = {}, a1 = {};
#pragma unroll
        for (int kc = 0; kc < 2; ++kc) {
          a0 = mfma(ai0[kc], frag(bx0, kc), a0);
          a1 = mfma(ai0[kc], frag(bx1, kc), a1);
        }
#pragma unroll
        for (int kc = 0; kc < 8; ++kc) {
          a0 = mfma(ah0[kc], frag(bh0, kc), a0);
          a1 = mfma(ah0[kc], frag(bh1, kc), a1);
        }
        epi1(HB(0, np), bias, a0, mt * 32, 0,  l31, hf);
        epi1(HB(0, np), bias, a1, mt * 32, 32, l31, hf);
      }
      if (xact) {
        half4v h4a, h4b;
#pragma unroll
        for (int j = 0; j < 4; ++j) { h4a[j] = (half_t)xq0[j]; h4b[j] = (half_t)xq1[j]; }
        *(half4v*)&XB(np)[xrow * XSTR + xch * 4] = h4a;
        *(half4v*)&XB(np)[(xrow + 32) * XSTR + xch * 4] = h4b;
      }
      __syncthreads();
    }
  } else if (wid < 8) {
    // ---- L1 (reuse): 2 m-tiles x 1 n-tile ----
    const int mp = (wid - 4) & 1;        // m-pair: tiles {2mp, 2mp+1}
    const int nt = (wid - 4) >> 1;       // n-tile: batch cols [nt*32, +32)
    half8 wi[2][8], wh[2][8];            // 128 VGPRs, held all 28 steps
    loadw8(wi[0], wih1, (2 * mp) * 32 + l31, hf);
    loadw8(wi[1], wih1, (2 * mp + 1) * 32 + l31, hf);
    loadw8(wh[0], whh1, (2 * mp) * 32 + l31, hf);
    loadw8(wh[1], whh1, (2 * mp + 1) * 32 + l31, hf);
    for (int i = 0; i < T_ + 2; ++i) {
      const int p = i & 1, np = p ^ 1;
      if (i >= 1 && i < T_ + 1) {
        const half_t* bi = HB(0, p) + (nt * 32 + l31) * HSTR + hf * 8;  // h0[t=i-1]
        const half_t* br = HB(1, p) + (nt * 32 + l31) * HSTR + hf * 8;  // h1[t=i-2]
        f32x16 a0, a1;
        mm2m(bi, br, wi, wh, a0, a1);
        epi1(HB(1, np), bias + H_, a0, (2 * mp) * 32,     nt * 32, l31, hf);
        epi1(HB(1, np), bias + H_, a1, (2 * mp + 1) * 32, nt * 32, l31, hf);
      }
      __syncthreads();
    }
  } else {
    // ---- L2 (reuse): 2 m-tiles x 1 n-tile ----
    const int mp = (wid - 8) & 1;
    const int nt = (wid - 8) >> 1;
    half8 wi[2][8], wh[2][8];
    loadw8(wi[0], wih2, (2 * mp) * 32 + l31, hf);
    loadw8(wi[1], wih2, (2 * mp + 1) * 32 + l31, hf);
    loadw8(wh[0], whh2, (2 * mp) * 32 + l31, hf);
    loadw8(wh[1], whh2, (2 * mp + 1) * 32 + l31, hf);
    for (int i = 0; i < T_ + 2; ++i) {
      const int p = i & 1, np = p ^ 1;
      if (i >= 2) {
        const half_t* bi = HB(1, p) + (nt * 32 + l31) * HSTR + hf * 8;  // h1[t=i-2]
        const half_t* br = HB(2, p) + (nt * 32 + l31) * HSTR + hf * 8;  // h2[t=i-3]
        f32x16 a0, a1;
        mm2m(bi, br, wi, wh, a0, a1);
        epi1(HB(2, np), bias + 2 * H_, a0, (2 * mp) * 32,     nt * 32, l31, hf);
        epi1(HB(2, np), bias + 2 * H_, a1, (2 * mp + 1) * 32, nt * 32, l31, hf);
      }
      __syncthreads();
    }
  }
  // last in-loop barrier (i=29) makes final h2 (parity 0) visible

  // ---- FC head: out[b][c] = h2_last[b] . fcw[c] + fcb[c] ----
  if (tid < 512) {
    const half_t* h2f = HB(2, 0);
    const int row = tid >> 3, q = tid & 7;
    for (int c = q; c < C_; c += 8) {
      float s = fcb[c];
      const float* wp = fcw + c * H_;
#pragma unroll
      for (int k = 0; k < H_; k += 8) {
        const half8 hv = *(const half8*)&h2f[row * HSTR + k];
#pragma unroll
        for (int j = 0; j < 8; ++j) s += (float)hv[j] * wp[k + j];
      }
      out[(size_t)(b0 + row) * C_ + c] = s;
    }
  }
#undef HB
#undef XB
}

extern "C" void kernel_launch(void* const* d_in, const int* in_sizes, int n_in,
                              void* d_out, int out_size, void* d_ws, size_t ws_size,
                              hipStream_t stream)
{
  const float* x    = (const float*)d_in[0];
  const float* wih0 = (const float*)d_in[1];
  const float* whh0 = (const float*)d_in[2];
  const float* bih0 = (const float*)d_in[3];
  const float* bhh0 = (const float*)d_in[4];
  const float* wih1 = (const float*)d_in[5];
  const float* whh1 = (const float*)d_in[6];
  const float* bih1 = (const float*)d_in[7];
  const float* bhh1 = (const float*)d_in[8];
  const float* wih2 = (const float*)d_in[9];
  const float* whh2 = (const float*)d_in[10];
  const float* bih2 = (const float*)d_in[11];
  const float* bhh2 = (const float*)d_in[12];
  const float* fcw  = (const float*)d_in[13];
  const float* fcb  = (const float*)d_in[14];
  float* out = (float*)d_out;

  (void)hipFuncSetAttribute((const void*)rnn_pipe,
                            hipFuncAttributeMaxDynamicSharedMemorySize, (int)SM_BYTES);

  rnn_pipe<<<B_ / BT, NT, SM_BYTES, stream>>>(x,
      wih0, whh0, bih0, bhh0,
      wih1, whh1, bih1, bhh1,
      wih2, whh2, bih2, bhh2,
      fcw, fcb, out);
}

// Round 10
// 180.689 us; speedup vs baseline: 1.1118x; 1.1118x over previous
//
#include <hip/hip_runtime.h>

typedef _Float16 half_t;
typedef _Float16 half8  __attribute__((ext_vector_type(8)));
typedef _Float16 half4v __attribute__((ext_vector_type(4)));
typedef float    f32x16 __attribute__((ext_vector_type(16)));
typedef float    f32x4  __attribute__((ext_vector_type(4)));

#define DEVI static __device__ __forceinline__

constexpr int B_  = 16384;
constexpr int T_  = 28;
constexpr int IN_ = 28;
constexpr int H_  = 128;
constexpr int C_  = 11;
constexpr int BT  = 64;    // batch rows per block; grid = 256 = 1 block/CU
constexpr int NT  = 768;   // 12 waves: 4x L0, 4x L1, 4x L2 (R8 shapes: proven no-spill)
constexpr int HSTR = 136;  // LDS stride (halves): 272B rows, 16B-aligned, balanced banks
constexpr int XSTR = 40;

constexpr int HBUF = BT * HSTR;
constexpr int XBUF = BT * XSTR;
constexpr int SM_HALVES = 6 * HBUF + 2 * XBUF;  // h[3][2] + xin[2]
constexpr int NFLAG = 8 * 32;                   // 8 counter arrays x 32 steps
constexpr size_t SM_BYTES = (size_t)SM_HALVES * 2 + 3 * H_ * 4 + NFLAG * 4;  // 117248 B

DEVI f32x16 mfma(half8 a, half8 b, f32x16 c) {
  return __builtin_amdgcn_mfma_f32_32x32x16_f16(a, b, c, 0, 0, 0);
}

DEVI half8 frag(const half_t* base, int kc) { return *(const half8*)(base + kc * 16); }

// A-fragments, one 32-row m-tile of a 128x128 row-major fp32 matrix.
// A layout (32x32x16 f16, validated R2-R9): lane holds A[m=lane&31][k=(lane>>5)*8+j].
DEVI void loadw8(half8 d[8], const float* __restrict__ w, int mrow, int hf) {
  const float* p = w + mrow * H_ + hf * 8;
#pragma unroll
  for (int kc = 0; kc < 8; ++kc) {
    half8 f;
#pragma unroll
    for (int j = 0; j < 8; ++j) f[j] = (half_t)p[kc * 16 + j];
    d[kc] = f;
  }
}

// h = relu(acc + bias) -> hout.  C/D layout (HW-verified m74/m101):
// col = lane&31 (batch), row = (reg&3)+8*(reg>>2)+4*(lane>>5).
DEVI void epi1(half_t* __restrict__ hout, const float* __restrict__ bl,
               f32x16 a, int mrow0, int ncol0, int l31, int hf) {
#pragma unroll
  for (int rq = 0; rq < 4; ++rq) {
    const int n0 = mrow0 + rq * 8 + hf * 4;
    const f32x4 b4 = *(const f32x4*)&bl[n0];
    half4v h4;
#pragma unroll
    for (int ri = 0; ri < 4; ++ri)
      h4[ri] = (half_t)fmaxf(a[rq * 4 + ri] + b4[ri], 0.0f);
    *(half4v*)&hout[(ncol0 + l31) * HSTR + n0] = h4;
  }
}

// ---- producer/consumer flag ops (LDS, workgroup scope) ----
DEVI void waitge(int* f, int v) {
  while (__hip_atomic_load(f, __ATOMIC_ACQUIRE, __HIP_MEMORY_SCOPE_WORKGROUP) < v)
    __builtin_amdgcn_s_sleep(1);
}
DEVI void bump(int* f) {
  __hip_atomic_fetch_add(f, 1, __ATOMIC_RELEASE, __HIP_MEMORY_SCOPE_WORKGROUP);
}

__global__ __launch_bounds__(NT) __attribute__((amdgpu_waves_per_eu(3)))
void rnn_pipe(const float* __restrict__ x,
              const float* __restrict__ wih0, const float* __restrict__ whh0,
              const float* __restrict__ bih0, const float* __restrict__ bhh0,
              const float* __restrict__ wih1, const float* __restrict__ whh1,
              const float* __restrict__ bih1, const float* __restrict__ bhh1,
              const float* __restrict__ wih2, const float* __restrict__ whh2,
              const float* __restrict__ bih2, const float* __restrict__ bhh2,
              const float* __restrict__ fcw, const float* __restrict__ fcb,
              float* __restrict__ out)
{
  extern __shared__ __align__(16) char smraw[];
  half_t* hs   = (half_t*)smraw;
  float*  bias = (float*)(hs + SM_HALVES);
  int*    fl   = (int*)(bias + 3 * H_);
  // Counter arrays, each indexed by idx = t + 2 (t = step, so t=-2..-1 have presets):
  int* prx = fl;        // x[t] staged       (target 4)
  int* rdx = fl + 32;   // x[t] readers done (target 4: the 4 L0 waves)
  int* pr0 = fl + 64;   // h0[t] produced    (target 4)
  int* rd0 = fl + 96;   // h0[t] readers done(target 8: 4 L0@t+1 + 4 L1@t)
  int* pr1 = fl + 128;  // h1[t] produced    (target 4)
  int* rd1 = fl + 160;  // h1[t] readers done(target 8: 4 L1@t+1 + 4 L2@t)
  int* pr2 = fl + 192;  // h2[t] produced    (target 4)
  int* rd2 = fl + 224;  // h2[t] readers done(target 4: 4 L2@t+1)
#define HB(l, b) (hs + ((l) * 2 + (b)) * HBUF)
#define XB(b)    (hs + 6 * HBUF + (b) * XBUF)

  const int tid  = threadIdx.x;
  const int b0   = blockIdx.x * BT;
  const int lane = tid & 63;
  const int wid  = tid >> 6;
  const int l31  = lane & 31;
  const int hf   = lane >> 5;

  // ---- init: zero LDS buffers + flags, stage biases + x[0], presets ----
  for (int i = tid; i < SM_HALVES / 2; i += NT) ((unsigned int*)hs)[i] = 0u;
  for (int i = tid; i < NFLAG; i += NT) fl[i] = 0;
  if (tid < H_) {
    bias[tid]          = bih0[tid] + bhh0[tid];
    bias[H_ + tid]     = bih1[tid] + bhh1[tid];
    bias[2 * H_ + tid] = bih2[tid] + bhh2[tid];
  }
  if (tid < 512) {  // stage x[t=0] into XB(0)
    const int row = tid >> 3, ch = tid & 7;
    if (ch < 7) {
      const f32x4 v = *(const f32x4*)(x + (size_t)(b0 + row) * (T_ * IN_) + ch * 4);
      half4v h4;
#pragma unroll
      for (int j = 0; j < 4; ++j) h4[j] = (half_t)v[j];
      *(half4v*)&XB(0)[row * XSTR + ch * 4] = h4;
    }
  }
  if (tid == 0) {  // presets for t<0 (h_l[-1]=0 lives in buffer 1, zeroed above)
    pr0[1] = 4; pr1[1] = 4; pr2[1] = 4;
    rd0[0] = 8; rd0[1] = 8; rd1[0] = 8; rd1[1] = 8;
    rd2[0] = 4; rd2[1] = 4; rdx[0] = 4; rdx[1] = 4;
    prx[2] = 4;  // x[0] staged in this prologue
  }
  __syncthreads();

  // ===== flag-synced pipeline: NO block barrier in the main loop.
  // h_l[t] lives in HB(l, t&1); x[t] in XB(t&1). Waves drift freely within
  // the double-buffer window; LDS FIFO stays fed, MFMA overlaps other waves' reads.
  if (wid < 4) {
    // ---- L0: 1 m-tile, 2 n-tiles; stages x[t+1] ----
    const int mt = wid;
    half8 ai0[2], ah0[8];
    loadw8(ah0, whh0, mt * 32 + l31, hf);
#pragma unroll
    for (int kc = 0; kc < 2; ++kc) {  // wih0: K=28 padded to 32 with zeros
      half8 f;
#pragma unroll
      for (int j = 0; j < 8; ++j) {
        const int k = kc * 16 + hf * 8 + j;
        f[j] = (k < IN_) ? (half_t)wih0[(mt * 32 + l31) * IN_ + k] : (half_t)0.0f;
      }
      ai0[kc] = f;
    }
    const int xrow = tid >> 3, xch = tid & 7;  // tid<256: rows 0..31 (+32 second)
    for (int t = 0; t < T_; ++t) {
      const int bp = t & 1;
      const bool xact = (xch < 7) && (t + 1 < T_);
      f32x4 xq0, xq1;
      if (xact) {  // issue global loads before the spins; latency hidden
        const float* xp = x + (size_t)(t + 1) * IN_ + xch * 4;
        xq0 = *(const f32x4*)(xp + (size_t)(b0 + xrow) * (T_ * IN_));
        xq1 = *(const f32x4*)(xp + (size_t)(b0 + xrow + 32) * (T_ * IN_));
      }
      waitge(&prx[t + 2], 4);   // x[t] staged
      waitge(&pr0[t + 1], 4);   // h0[t-1] complete
      waitge(&rd0[t], 8);       // h0 buffer bp free (readers of h0[t-2] done)
      {
        const half_t* bx0 = XB(bp) + l31 * XSTR + hf * 8;
        const half_t* bx1 = XB(bp) + (32 + l31) * XSTR + hf * 8;
        const half_t* bh0 = HB(0, bp ^ 1) + l31 * HSTR + hf * 8;
        const half_t* bh1 = HB(0, bp ^ 1) + (32 + l31) * HSTR + hf * 8;
        f32x16 a0 = {}, a1 = {};
#pragma unroll
        for (int kc = 0; kc < 2; ++kc) {
          a0 = mfma(ai0[kc], frag(bx0, kc), a0);
          a1 = mfma(ai0[kc], frag(bx1, kc), a1);
        }
#pragma unroll
        for (int kc = 0; kc < 8; ++kc) {
          a0 = mfma(ah0[kc], frag(bh0, kc), a0);
          a1 = mfma(ah0[kc], frag(bh1, kc), a1);
        }
        __threadfence_block();  // reads done (MFMAs consumed them)
        if (lane == 0) { bump(&rdx[t + 2]); bump(&rd0[t + 1]); }
        epi1(HB(0, bp), bias, a0, mt * 32, 0,  l31, hf);
        epi1(HB(0, bp), bias, a1, mt * 32, 32, l31, hf);
        __threadfence_block();  // epi writes visible
        if (lane == 0) bump(&pr0[t + 2]);
      }
      if (xact) {
        waitge(&rdx[t + 1], 4);  // x buffer bp^1 free (readers of x[t-1] done)
        half4v h4a, h4b;
#pragma unroll
        for (int j = 0; j < 4; ++j) { h4a[j] = (half_t)xq0[j]; h4b[j] = (half_t)xq1[j]; }
        *(half4v*)&XB(bp ^ 1)[xrow * XSTR + xch * 4] = h4a;
        *(half4v*)&XB(bp ^ 1)[(xrow + 32) * XSTR + xch * 4] = h4b;
        __threadfence_block();
        if (lane == 0) bump(&prx[t + 3]);
      } else if (t + 1 < T_ && lane == 0) {
        bump(&prx[t + 3]);  // keep counter protocol exact even for xch>=7 lanes? (wave-level: xact is uniform per wave except xch — see note)
      }
      // NOTE: xact differs per-lane via xch<7, but stores are per-lane and the
      // bump is lane==0 (xch=0 -> xact true whenever t+1<T_), so exactly one
      // bump per wave per staged step. The else-branch above never fires for
      // lane 0; it is dead code kept for clarity.
    }
  } else if (wid < 8) {
    // ---- L1: 1 m-tile, 2 n-tiles ----
    const int mt1 = wid - 4;
    half8 wi[8], wh[8];
    loadw8(wi, wih1, mt1 * 32 + l31, hf);
    loadw8(wh, whh1, mt1 * 32 + l31, hf);
    for (int t = 0; t < T_; ++t) {
      const int bp = t & 1;
      waitge(&pr0[t + 2], 4);   // h0[t] complete
      waitge(&pr1[t + 1], 4);   // h1[t-1] complete
      waitge(&rd1[t], 8);       // h1 buffer bp free
      const half_t* bi0 = HB(0, bp) + l31 * HSTR + hf * 8;
      const half_t* bi1 = HB(0, bp) + (32 + l31) * HSTR + hf * 8;
      const half_t* br0 = HB(1, bp ^ 1) + l31 * HSTR + hf * 8;
      const half_t* br1 = HB(1, bp ^ 1) + (32 + l31) * HSTR + hf * 8;
      f32x16 a0 = {}, a1 = {};
#pragma unroll
      for (int kc = 0; kc < 8; ++kc) {
        a0 = mfma(wi[kc], frag(bi0, kc), a0);
        a1 = mfma(wi[kc], frag(bi1, kc), a1);
      }
#pragma unroll
      for (int kc = 0; kc < 8; ++kc) {
        a0 = mfma(wh[kc], frag(br0, kc), a0);
        a1 = mfma(wh[kc], frag(br1, kc), a1);
      }
      __threadfence_block();
      if (lane == 0) { bump(&rd0[t + 2]); bump(&rd1[t + 1]); }
      epi1(HB(1, bp), bias + H_, a0, mt1 * 32, 0,  l31, hf);
      epi1(HB(1, bp), bias + H_, a1, mt1 * 32, 32, l31, hf);
      __threadfence_block();
      if (lane == 0) bump(&pr1[t + 2]);
    }
  } else {
    // ---- L2: 1 m-tile, 2 n-tiles ----
    const int mt2 = wid - 8;
    half8 wi[8], wh[8];
    loadw8(wi, wih2, mt2 * 32 + l31, hf);
    loadw8(wh, whh2, mt2 * 32 + l31, hf);
    for (int t = 0; t < T_; ++t) {
      const int bp = t & 1;
      waitge(&pr1[t + 2], 4);   // h1[t] complete
      waitge(&pr2[t + 1], 4);   // h2[t-1] complete
      waitge(&rd2[t], 4);       // h2 buffer bp free
      const half_t* bi0 = HB(1, bp) + l31 * HSTR + hf * 8;
      const half_t* bi1 = HB(1, bp) + (32 + l31) * HSTR + hf * 8;
      const half_t* br0 = HB(2, bp ^ 1) + l31 * HSTR + hf * 8;
      const half_t* br1 = HB(2, bp ^ 1) + (32 + l31) * HSTR + hf * 8;
      f32x16 a0 = {}, a1 = {};
#pragma unroll
      for (int kc = 0; kc < 8; ++kc) {
        a0 = mfma(wi[kc], frag(bi0, kc), a0);
        a1 = mfma(wi[kc], frag(bi1, kc), a1);
      }
#pragma unroll
      for (int kc = 0; kc < 8; ++kc) {
        a0 = mfma(wh[kc], frag(br0, kc), a0);
        a1 = mfma(wh[kc], frag(br1, kc), a1);
      }
      __threadfence_block();
      if (lane == 0) { bump(&rd1[t + 2]); bump(&rd2[t + 1]); }
      epi1(HB(2, bp), bias + 2 * H_, a0, mt2 * 32, 0,  l31, hf);
      epi1(HB(2, bp), bias + 2 * H_, a1, mt2 * 32, 32, l31, hf);
      __threadfence_block();
      if (lane == 0) bump(&pr2[t + 2]);
    }
  }

  // ---- wait for h2[27] (idx 29), then FC head; h2[27] is in buffer 27&1 = 1 ----
  waitge(&pr2[T_ + 1], 4);
  if (tid < 512) {
    const half_t* h2f = HB(2, 1);
    const int row = tid >> 3, q = tid & 7;
    for (int c = q; c < C_; c += 8) {
      float s = fcb[c];
      const float* wp = fcw + c * H_;
#pragma unroll
      for (int k = 0; k < H_; k += 8) {
        const half8 hv = *(const half8*)&h2f[row * HSTR + k];
#pragma unroll
        for (int j = 0; j < 8; ++j) s += (float)hv[j] * wp[k + j];
      }
      out[(size_t)(b0 + row) * C_ + c] = s;
    }
  }
#undef HB
#undef XB
}

extern "C" void kernel_launch(void* const* d_in, const int* in_sizes, int n_in,
                              void* d_out, int out_size, void* d_ws, size_t ws_size,
                              hipStream_t stream)
{
  const float* x    = (const float*)d_in[0];
  const float* wih0 = (const float*)d_in[1];
  const float* whh0 = (const float*)d_in[2];
  const float* bih0 = (const float*)d_in[3];
  const float* bhh0 = (const float*)d_in[4];
  const float* wih1 = (const float*)d_in[5];
  const float* whh1 = (const float*)d_in[6];
  const float* bih1 = (const float*)d_in[7];
  const float* bhh1 = (const float*)d_in[8];
  const float* wih2 = (const float*)d_in[9];
  const float* whh2 = (const float*)d_in[10];
  const float* bih2 = (const float*)d_in[11];
  const float* bhh2 = (const float*)d_in[12];
  const float* fcw  = (const float*)d_in[13];
  const float* fcb  = (const float*)d_in[14];
  float* out = (float*)d_out;

  (void)hipFuncSetAttribute((const void*)rnn_pipe,
                            hipFuncAttributeMaxDynamicSharedMemorySize, (int)SM_BYTES);

  rnn_pipe<<<B_ / BT, NT, SM_BYTES, stream>>>(x,
      wih0, whh0, bih0, bhh0,
      wih1, whh1, bih1, bhh1,
      wih2, whh2, bih2, bhh2,
      fcw, fcb, out);
}